// Round 3
// baseline (173.621 us; speedup 1.0000x reference)
//
#include <hip/hip_runtime.h>
#include <math.h>

// QMIX mixing network, B=65536, A=8, S=256, E=32. All tensors fp32.
// GEMM: bf16(states)[B,256] @ bf16(Wcat)[256,352] via mfma_f32_16x16x32_bf16,
// fp32 accumulate, fused epilogue. Barrier-free main loop: A and B fragments
// loaded straight from global (A has no cross-wave reuse; B is L1-resident).
// Wcat columns: [0,256)=w1_W, [256,288)=wf_W, [288,320)=b1_W, [320,352)=v1_W.

#define NTILES 22      // 352/16
#define KCHUNKS 8      // 256/32
#define BPERKC 11264   // 22*64*8 bf16 elements per k-chunk of repacked B

typedef __attribute__((ext_vector_type(8))) short short8;
typedef __attribute__((ext_vector_type(4))) float float4v;

__device__ __forceinline__ unsigned short f2b(float f) {
    unsigned int u = __float_as_uint(f);
    u = u + 0x7fffu + ((u >> 16) & 1u);   // RNE
    return (unsigned short)(u >> 16);
}

// Repack fp32 Wcat into bf16 MFMA B-fragment order: brep[kc][tile][lane][j] =
// bf16(W[k = kc*32 + (lane>>4)*8 + j][n = tile*16 + (lane&15)]).
// One thread per fragment: 8 strided reads, one contiguous 16B write.
__global__ void repack_b(const float* __restrict__ w1_W,
                         const float* __restrict__ wf_W,
                         const float* __restrict__ b1_W,
                         const float* __restrict__ v1_W,
                         unsigned short* __restrict__ brep) {
    int idx = blockIdx.x * 256 + threadIdx.x;   // 0..11263 = (kc*22 + tile)*64 + lane
    int lane = idx & 63;
    int tt   = idx >> 6;          // 0..175 = kc*22 + tile
    int tile = tt % 22;
    int kc   = tt / 22;
    int kbase = kc * 32 + (lane >> 4) * 8;
    int n = tile * 16 + (lane & 15);
    short8 frag;
#pragma unroll
    for (int j = 0; j < 8; ++j) {
        int k = kbase + j;
        float val;
        if (n < 256)      val = w1_W[k * 256 + n];
        else if (n < 288) val = wf_W[k * 32 + (n - 256)];
        else if (n < 320) val = b1_W[k * 32 + (n - 288)];
        else              val = v1_W[k * 32 + (n - 320)];
        frag[j] = (short)f2b(val);
    }
    *(short8*)(&brep[idx * 8]) = frag;
}

__global__ void __launch_bounds__(256, 3)
qmix_main(const float* __restrict__ agent_qs,
          const float* __restrict__ states,
          const unsigned short* __restrict__ brep,
          const float* __restrict__ w1_b,
          const float* __restrict__ wf_b,
          const float* __restrict__ b1_b,
          const float* __restrict__ v1_b,
          const float* __restrict__ v2_W,
          const float* __restrict__ v2_b,
          float* __restrict__ out) {
    // Only LDS: per-wave epilogue dump, 16 rows x 20 floats (pad to 20), 4 waves.
    __shared__ __align__(16) float dump_lds[4 * 320];

    const int tid  = threadIdx.x;
    const int wave = tid >> 6, lane = tid & 63;
    const int quad = lane >> 4, l16 = lane & 15;
    const int rowA = blockIdx.x * 64 + wave * 16 + l16;   // A-operand row (m = l16)
    const float* arow = states + (size_t)rowA * 256;

    // ---- Hoist all A fragments: afr[kc] = bf16(A[m=l16][k=kc*32+quad*8 .. +7]) ----
    short8 afr[KCHUNKS];
#pragma unroll
    for (int kc = 0; kc < KCHUNKS; ++kc) {
        float4v a0 = *(const float4v*)(arow + kc * 32 + quad * 8);
        float4v a1 = *(const float4v*)(arow + kc * 32 + quad * 8 + 4);
        short8 af;
#pragma unroll
        for (int j = 0; j < 4; ++j) {
            af[j]     = (short)f2b(a0[j]);
            af[4 + j] = (short)f2b(a1[j]);
        }
        afr[kc] = af;
    }

    float4v acc[NTILES];
#pragma unroll
    for (int t = 0; t < NTILES; ++t)
#pragma unroll
        for (int q = 0; q < 4; ++q) acc[t][q] = 0.f;

    // ---- K loop: no barriers, no LDS. B fragments straight from L1/L2. ----
    const short8* bfr = (const short8*)brep + lane;   // + kc*1408 + t*64
    for (int kc = 0; kc < KCHUNKS; ++kc) {
        short8 af = afr[kc];
        const short8* bk = bfr + kc * 1408;
#pragma unroll
        for (int t = 0; t < NTILES; ++t) {
            short8 bf = bk[t * 64];
            acc[t] = __builtin_amdgcn_mfma_f32_16x16x32_bf16(af, bf, acc[t], 0, 0, 0);
        }
    }

    // ---- Epilogue (wave-synchronous; lanes of a wave run in lockstep) ----
    float* dump = dump_lds + wave * 320;
    const int r = lane >> 2, p = lane & 3;      // 4 lanes cooperate per output row
    const int row = blockIdx.x * 64 + wave * 16 + r;

    float qacc[8], wfv[8], b1v[8], svp = 0.f;
#pragma unroll
    for (int s = 0; s < 8; ++s) qacc[s] = 0.f;

#pragma unroll
    for (int t = 0; t < NTILES; ++t) {
        // D layout: col = lane&15, row = quad*4 + reg  (m89/m91 verified)
#pragma unroll
        for (int reg = 0; reg < 4; ++reg)
            dump[(quad * 4 + reg) * 20 + l16] = acc[t][reg];
        __threadfence_block();                 // lgkmcnt(0) + compiler barrier
        float4v v = *(const float4v*)(&dump[r * 20 + p * 4]);

        const float* bptr =
            (t < 16) ? (w1_b + t * 16) :
            (t < 18) ? (wf_b + (t - 16) * 16) :
            (t < 20) ? (b1_b + (t - 18) * 16) : (v1_b + (t - 20) * 16);
        float vb[4];
#pragma unroll
        for (int j = 0; j < 4; ++j) vb[j] = v[j] + bptr[p * 4 + j];

        if (t < 16) {              // w1 region: n = a*32 + e; a = t>>1, e = (t&1)*16 + p*4 + j
            float q = agent_qs[row * 8 + (t >> 1)];
            int base = (t & 1) * 4;
#pragma unroll
            for (int j = 0; j < 4; ++j) qacc[base + j] += q * fabsf(vb[j]);
        } else if (t < 18) {       // w_final
            int base = (t - 16) * 4;
#pragma unroll
            for (int j = 0; j < 4; ++j) wfv[base + j] = fabsf(vb[j]);
        } else if (t < 20) {       // b1
            int base = (t - 18) * 4;
#pragma unroll
            for (int j = 0; j < 4; ++j) b1v[base + j] = vb[j];
        } else {                   // V hidden: relu -> dot v2_W
            int ebase = (t - 20) * 16 + p * 4;
#pragma unroll
            for (int j = 0; j < 4; ++j)
                svp += fmaxf(vb[j], 0.f) * v2_W[ebase + j];
        }
        __threadfence_block();                 // reads done before next tile's writes
    }

    float m = 0.f;
#pragma unroll
    for (int s = 0; s < 8; ++s) {
        float h = qacc[s] + b1v[s];
        h = h > 0.f ? h : expm1f(h);           // elu, alpha=1
        m += h * wfv[s];
    }
    float tot = m + svp;
    tot += __shfl_xor(tot, 1);                 // sum over the 4 cooperating lanes
    tot += __shfl_xor(tot, 2);
    if (p == 0) out[row] = tot + v2_b[0];
}

extern "C" void kernel_launch(void* const* d_in, const int* in_sizes, int n_in,
                              void* d_out, int out_size, void* d_ws, size_t ws_size,
                              hipStream_t stream) {
    const float* agent_qs = (const float*)d_in[0];
    const float* states   = (const float*)d_in[1];
    const float* w1_W = (const float*)d_in[2];
    const float* w1_b = (const float*)d_in[3];
    const float* wf_W = (const float*)d_in[4];
    const float* wf_b = (const float*)d_in[5];
    const float* b1_W = (const float*)d_in[6];
    const float* b1_b = (const float*)d_in[7];
    const float* v1_W = (const float*)d_in[8];
    const float* v1_b = (const float*)d_in[9];
    const float* v2_W = (const float*)d_in[10];
    const float* v2_b = (const float*)d_in[11];
    float* out = (float*)d_out;
    unsigned short* brep = (unsigned short*)d_ws;    // 180224 B of scratch

    repack_b<<<44, 256, 0, stream>>>(w1_W, wf_W, b1_W, v1_W, brep);
    qmix_main<<<1024, 256, 0, stream>>>(agent_qs, states, brep,
                                        w1_b, wf_b, b1_b, v1_b, v2_W, v2_b, out);
}

// Round 4
// 152.508 us; speedup vs baseline: 1.1384x; 1.1384x over previous
//
#include <hip/hip_runtime.h>
#include <math.h>

// QMIX mixing network, B=65536, A=8, S=256, E=32. All tensors fp32.
// Transposed MFMA orientation: A-operand = bf16(Wcat^T) tiles (m = out col),
// B-operand = bf16(states^T) (n = batch row), mfma_f32_16x16x32_bf16.
// D: col(lane&15) = batch row, row(quad*4+reg) = out col -> epilogue fully
// in registers (no LDS, no barriers, no fences). Wcat columns:
// [0,256)=w1_W, [256,288)=wf_W, [288,320)=b1_W, [320,352)=v1_W.

#define NTILES 22      // 352/16
#define KCHUNKS 8      // 256/32

typedef __attribute__((ext_vector_type(8))) short short8;
typedef __attribute__((ext_vector_type(4))) float float4v;

__device__ __forceinline__ unsigned short f2b(float f) {
    unsigned int u = __float_as_uint(f);
    u = u + 0x7fffu + ((u >> 16) & 1u);   // RNE
    return (unsigned short)(u >> 16);
}

// Repack fp32 Wcat into bf16 fragment order (validated R1-R3):
// brep[(kc*22+tile)*64 + lane][j] = bf16(Wcat[k = kc*32+(lane>>4)*8+j][tile*16+(lane&15)])
// As A-operand: m = tile*16 + (lane&15), k = kc*32 + quad*8 + j  (same bytes).
__global__ void repack_b(const float* __restrict__ w1_W,
                         const float* __restrict__ wf_W,
                         const float* __restrict__ b1_W,
                         const float* __restrict__ v1_W,
                         unsigned short* __restrict__ brep) {
    int idx = blockIdx.x * 256 + threadIdx.x;   // 0..11263
    int lane = idx & 63;
    int tt   = idx >> 6;          // kc*22 + tile
    int tile = tt % 22;
    int kc   = tt / 22;
    int kbase = kc * 32 + (lane >> 4) * 8;
    int n = tile * 16 + (lane & 15);
    short8 frag;
#pragma unroll
    for (int j = 0; j < 8; ++j) {
        int k = kbase + j;
        float val;
        if (n < 256)      val = w1_W[k * 256 + n];
        else if (n < 288) val = wf_W[k * 32 + (n - 256)];
        else if (n < 320) val = b1_W[k * 32 + (n - 288)];
        else              val = v1_W[k * 32 + (n - 320)];
        frag[j] = (short)f2b(val);
    }
    *(short8*)(&brep[idx * 8]) = frag;
}

__global__ void __launch_bounds__(256, 3)
qmix_main(const float* __restrict__ agent_qs,
          const float* __restrict__ states,
          const unsigned short* __restrict__ brep,
          const float* __restrict__ w1_b,
          const float* __restrict__ wf_b,
          const float* __restrict__ b1_b,
          const float* __restrict__ v1_b,
          const float* __restrict__ v2_W,
          const float* __restrict__ v2_b,
          float* __restrict__ out) {
    const int tid  = threadIdx.x;
    const int wave = tid >> 6, lane = tid & 63;
    const int quad = lane >> 4, l16 = lane & 15;
    const int row  = blockIdx.x * 64 + wave * 16 + l16;   // this lane's batch row (n)
    const float* srow = states + (size_t)row * 256;

    // ---- B fragments (states^T): bfr[kc][j] = bf16(states[row][kc*32+quad*8+j]) ----
    short8 bfr[KCHUNKS];
#pragma unroll
    for (int kc = 0; kc < KCHUNKS; ++kc) {
        float4v a0 = *(const float4v*)(srow + kc * 32 + quad * 8);
        float4v a1 = *(const float4v*)(srow + kc * 32 + quad * 8 + 4);
        short8 bf;
#pragma unroll
        for (int j = 0; j < 4; ++j) {
            bf[j]     = (short)f2b(a0[j]);
            bf[4 + j] = (short)f2b(a1[j]);
        }
        bfr[kc] = bf;
    }

    float4v acc[NTILES];
#pragma unroll
    for (int t = 0; t < NTILES; ++t)
#pragma unroll
        for (int q = 0; q < 4; ++q) acc[t][q] = 0.f;

    // ---- K loop: A-frags (weights) streamed from L1/L2, no LDS, no barriers ----
    for (int kc = 0; kc < KCHUNKS; ++kc) {
        const short8* ap = (const short8*)brep + kc * 1408 + lane;
        short8 bf = bfr[kc];
#pragma unroll
        for (int t = 0; t < NTILES; ++t) {
            short8 af = ap[t * 64];
            acc[t] = __builtin_amdgcn_mfma_f32_16x16x32_bf16(af, bf, acc[t], 0, 0, 0);
        }
    }

    // ---- Epilogue: all in registers. Lane holds, for batch row `row`,
    // out-cols m = tile*16 + quad*4 + reg. Slot s = parity*4 + reg, e = (s>>2)*16 + quad*4 + (s&3).
    float4v q0 = *(const float4v*)(agent_qs + (size_t)row * 8);
    float4v q1 = *(const float4v*)(agent_qs + (size_t)row * 8 + 4);
    float qv[8] = {q0[0], q0[1], q0[2], q0[3], q1[0], q1[1], q1[2], q1[3]};

    float qacc[8], wfv[8], b1v[8], svp = 0.f;
#pragma unroll
    for (int s = 0; s < 8; ++s) qacc[s] = 0.f;

#pragma unroll
    for (int t = 0; t < NTILES; ++t) {
        const float* bptr =
            (t < 16) ? (w1_b + t * 16) :
            (t < 18) ? (wf_b + (t - 16) * 16) :
            (t < 20) ? (b1_b + (t - 18) * 16) : (v1_b + (t - 20) * 16);
        float4v bb = *(const float4v*)(bptr + quad * 4);
        float vb[4];
#pragma unroll
        for (int j = 0; j < 4; ++j) vb[j] = acc[t][j] + bb[j];

        if (t < 16) {              // w1: agent a = t>>1, slot base = (t&1)*4
            float q = qv[t >> 1];
            int base = (t & 1) * 4;
#pragma unroll
            for (int j = 0; j < 4; ++j) qacc[base + j] += q * fabsf(vb[j]);
        } else if (t < 18) {       // w_final
            int base = (t - 16) * 4;
#pragma unroll
            for (int j = 0; j < 4; ++j) wfv[base + j] = fabsf(vb[j]);
        } else if (t < 20) {       // b1
            int base = (t - 18) * 4;
#pragma unroll
            for (int j = 0; j < 4; ++j) b1v[base + j] = vb[j];
        } else {                   // V hidden: relu -> dot v2_W, e = (t-20)*16 + quad*4 + j
            int ebase = (t - 20) * 16 + quad * 4;
#pragma unroll
            for (int j = 0; j < 4; ++j)
                svp += fmaxf(vb[j], 0.f) * v2_W[ebase + j];
        }
    }

    float mix = 0.f;
#pragma unroll
    for (int s = 0; s < 8; ++s) {
        float h = qacc[s] + b1v[s];
        h = h > 0.f ? h : (__expf(h) - 1.f);   // elu, alpha=1
        mix += h * wfv[s];
    }
    float tot = mix + svp;                      // partial over this quad's e-subset
    tot += __shfl_xor(tot, 16);                 // combine 4 quads (same batch row)
    tot += __shfl_xor(tot, 32);
    if (quad == 0) out[row] = tot + v2_b[0];
}

extern "C" void kernel_launch(void* const* d_in, const int* in_sizes, int n_in,
                              void* d_out, int out_size, void* d_ws, size_t ws_size,
                              hipStream_t stream) {
    const float* agent_qs = (const float*)d_in[0];
    const float* states   = (const float*)d_in[1];
    const float* w1_W = (const float*)d_in[2];
    const float* w1_b = (const float*)d_in[3];
    const float* wf_W = (const float*)d_in[4];
    const float* wf_b = (const float*)d_in[5];
    const float* b1_W = (const float*)d_in[6];
    const float* b1_b = (const float*)d_in[7];
    const float* v1_W = (const float*)d_in[8];
    const float* v1_b = (const float*)d_in[9];
    const float* v2_W = (const float*)d_in[10];
    const float* v2_b = (const float*)d_in[11];
    float* out = (float*)d_out;
    unsigned short* brep = (unsigned short*)d_ws;    // 180224 B of scratch

    repack_b<<<44, 256, 0, stream>>>(w1_W, wf_W, b1_W, v1_W, brep);
    qmix_main<<<1024, 256, 0, stream>>>(agent_qs, states, brep,
                                        w1_b, wf_b, b1_b, v1_b, v2_W, v2_b, out);
}